// Round 1
// baseline (2993.728 us; speedup 1.0000x reference)
//
#include <hip/hip_runtime.h>

// Conv4d: x(2,8,16,40,40,40) fp32 * w(3,32,8,3,3,3) + bias(3,32) -> out(2,32,16,40,40,40)
// Round 1: direct fp32 kernel.
// Block = (b, o, d, h-tile of 8): 6400 blocks x 256 threads (4 waves).
// Wave w owns co = 8w..8w+7 (wave-uniform -> LDS weight reads are broadcasts).
// Lane = (h_idx = lane>>3, wg = lane&7); thread computes 8co x 5w = 40 outputs.
// LDS: ws = k-slice of weights [216 r x 32 co, swizzled]; xs = 4ci x 3kd x 10hh rows, stride 43.

#define X_CI 8
#define X_T  16
#define SP   40

__global__ __launch_bounds__(256) void conv4d_direct(
    const float* __restrict__ x,
    const float* __restrict__ wgt,
    const float* __restrict__ bias,
    float* __restrict__ out)
{
    __shared__ float ws[216 * 32];   // [r=(ci,kd,kh,kw)][co rotated by 4*(r&7)]
    __shared__ float xs[120 * 43];   // [(cl,kd,hh)][padded w 0..41], row stride 43 (bank spread)

    const int bi = blockIdx.x;
    const int h0 = (bi % 5) * 8;
    const int d  = (bi / 5) % 40;
    const int o  = (bi / 200) % 16;
    const int b  = bi / 3200;

    const int tid  = threadIdx.x;
    const int lane = tid & 63;
    const int co0  = __builtin_amdgcn_readfirstlane((tid >> 6) * 8); // wave-uniform
    const int h_i  = lane >> 3;          // 0..7
    const int w0   = (lane & 7) * 5;     // 0,5,...,35

    float acc[8][5];
#pragma unroll
    for (int c = 0; c < 8; ++c)
#pragma unroll
        for (int i = 0; i < 5; ++i) acc[c][i] = 0.f;

    for (int k = 0; k < 3; ++k) {
        const int t = o + k - 1;
        if (t < 0 || t >= X_T) continue;   // block-uniform: bias+conv term both skipped

        // bias[k, co] contributes once per valid k (reference adds bias before T-pad)
#pragma unroll
        for (int c = 0; c < 8; ++c) {
            const float bv = bias[k * 32 + co0 + c];
#pragma unroll
            for (int i = 0; i < 5; ++i) acc[c][i] += bv;
        }

        for (int cih = 0; cih < 2; ++cih) {
            __syncthreads();
            if (cih == 0) {
                // stage weight k-slice, coalesced global read, swizzled LDS write
                for (int idx = tid; idx < 6912; idx += 256) {
                    const float v = wgt[k * 6912 + idx];
                    const int co = idx / 216;
                    const int r  = idx - co * 216;        // (ci,kd,kh,kw)
                    const int p  = (co + ((r & 7) << 2)) & 31;
                    ws[r * 32 + p] = v;
                }
            }
            // stage x rows for ci = 4*cih .. 4*cih+3
            for (int idx = tid; idx < 120 * 42; idx += 256) {
                const int row = idx / 42;
                const int col = idx - row * 42;
                const int cl  = row / 30;
                const int r2  = row - cl * 30;
                const int kd  = r2 / 10;
                const int hh  = r2 - kd * 10;
                const int ci  = cih * 4 + cl;
                const int da  = d + kd - 1;
                const int ha  = h0 + hh - 1;
                float v = 0.f;
                if (col >= 1 && col <= 40 && (unsigned)da < 40u && (unsigned)ha < 40u) {
                    v = x[(((b * X_CI + ci) * X_T + t) * SP + da) * 1600 + ha * 40 + (col - 1)];
                }
                xs[row * 43 + col] = v;
            }
            __syncthreads();

            for (int cl = 0; cl < 4; ++cl) {
                const int ci = cih * 4 + cl;
#pragma unroll
                for (int kd = 0; kd < 3; ++kd) {
#pragma unroll
                    for (int kh = 0; kh < 3; ++kh) {
                        const float* xr = &xs[((cl * 3 + kd) * 10 + h_i + kh) * 43 + w0];
                        float xv[7];
#pragma unroll
                        for (int j = 0; j < 7; ++j) xv[j] = xr[j];

                        const int rbw = ((ci * 3 + kd) * 3 + kh) * 3;
                        float wt[3][8];
#pragma unroll
                        for (int kw = 0; kw < 3; ++kw) {
                            const int r   = rbw + kw;
                            const int rot = (co0 + ((r & 7) << 2)) & 31;
                            const float4 q0 = *(const float4*)&ws[r * 32 + rot];
                            const float4 q1 = *(const float4*)&ws[r * 32 + ((rot + 4) & 31)];
                            wt[kw][0] = q0.x; wt[kw][1] = q0.y; wt[kw][2] = q0.z; wt[kw][3] = q0.w;
                            wt[kw][4] = q1.x; wt[kw][5] = q1.y; wt[kw][6] = q1.z; wt[kw][7] = q1.w;
                        }
#pragma unroll
                        for (int c = 0; c < 8; ++c)
#pragma unroll
                            for (int i = 0; i < 5; ++i)
                                acc[c][i] += xv[i]     * wt[0][c]
                                           + xv[i + 1] * wt[1][c]
                                           + xv[i + 2] * wt[2][c];
                    }
                }
            }
        }
    }

    // epilogue: out[b, co0+c, o, d, h0+h_i, w0+i]
    const int base = (((b * 32 + co0) * X_T + o) * SP + d) * 1600 + (h0 + h_i) * 40 + w0;
#pragma unroll
    for (int c = 0; c < 8; ++c) {
        float* op = out + base + c * 1024000;
#pragma unroll
        for (int i = 0; i < 5; ++i) op[i] = acc[c][i];
    }
}

extern "C" void kernel_launch(void* const* d_in, const int* in_sizes, int n_in,
                              void* d_out, int out_size, void* d_ws, size_t ws_size,
                              hipStream_t stream)
{
    const float* x    = (const float*)d_in[0];
    const float* wgt  = (const float*)d_in[1];
    const float* bias = (const float*)d_in[2];
    float* out = (float*)d_out;
    (void)d_ws; (void)ws_size; (void)in_sizes; (void)n_in; (void)out_size;
    conv4d_direct<<<dim3(6400), dim3(256), 0, stream>>>(x, wgt, bias, out);
}

// Round 2
// 367.332 us; speedup vs baseline: 8.1499x; 8.1499x over previous
//
#include <hip/hip_runtime.h>

// Conv4d: x(2,8,16,40,40,40) f32 * w(3,32,8,3,3,3) + bias(3,32) -> out(2,32,16,40,40,40) f32
// Round 2: bf16 MFMA implicit GEMM.
//   prep_x: x -> x_t[b][t][dp 42][hp 42][wp 42][ci 8] bf16, zero-padded d/h/w (+1 halo), in d_ws.
//   prep_w: weights -> exact A-fragment order Wf[kt][s 7][mt 2][lane 64][j 8] bf16 (K=216 pad 224).
//   main:   block=(b,o,d,h-tile8), 320 thr (5 waves); wave = 32co x 64n via mfma_f32_16x16x32_bf16.
//           K-order = (kd,kh,kw) combo * 8 + ci  ->  B-frag = ONE ds_read_b128 (ci contiguous).
//           Halo (3d' x 10h' x 42w' x 8ci = 20160B) staged via global_load_lds width 16.

typedef unsigned int u32;
typedef unsigned short u16;
typedef __attribute__((ext_vector_type(8))) short short8;
typedef __attribute__((ext_vector_type(4))) float f32x4;

#define XT_OFF_BYTES 65536
// x_t strides in elements (bf16): ci 1, wp 8, hp 336, dp 14112, t 592704, b 9483264

__device__ __forceinline__ u32 bf16r(float f) {
    u32 u = __float_as_uint(f);
    return (u + 0x7FFFu + ((u >> 16) & 1u)) >> 16;
}

__device__ __forceinline__ void glds16(const void* g, void* l) {
    __builtin_amdgcn_global_load_lds((const __attribute__((address_space(1))) u32*)g,
                                     (__attribute__((address_space(3))) u32*)l, 16, 0, 0);
}

// ---------- pre-kernel A: transpose/pad/convert x ----------
__global__ __launch_bounds__(256) void prep_x(const float* __restrict__ x, u16* __restrict__ xtp) {
    const int c = blockIdx.x * 256 + threadIdx.x;        // cell over [b][t][dp][hp][wp], 2370816 total
    int wp = c % 42;
    int tmp = c / 42;
    const int hp = tmp % 42; tmp /= 42;
    const int dp = tmp % 42; tmp /= 42;
    const int t  = tmp % 16;
    const int b  = tmp / 16;
    const int wa = wp - 1, ha = hp - 1, da = dp - 1;
    u32 q0 = 0, q1 = 0, q2 = 0, q3 = 0;
    if ((unsigned)wa < 40u && (unsigned)ha < 40u && (unsigned)da < 40u) {
        const float* xp = x + ((b * 8) * 16 + t) * 64000 + da * 1600 + ha * 40 + wa;
        float v0 = xp[0];
        float v1 = xp[1024000];
        float v2 = xp[2048000];
        float v3 = xp[3072000];
        float v4 = xp[4096000];
        float v5 = xp[5120000];
        float v6 = xp[6144000];
        float v7 = xp[7168000];
        q0 = bf16r(v0) | (bf16r(v1) << 16);
        q1 = bf16r(v2) | (bf16r(v3) << 16);
        q2 = bf16r(v4) | (bf16r(v5) << 16);
        q3 = bf16r(v6) | (bf16r(v7) << 16);
    }
    uint4 q; q.x = q0; q.y = q1; q.z = q2; q.w = q3;
    *(uint4*)(xtp + (size_t)c * 8) = q;
}

// ---------- pre-kernel B: weights -> A-fragment order ----------
__global__ __launch_bounds__(256) void prep_w(const float* __restrict__ wgt, u16* __restrict__ wf) {
    const int idx = blockIdx.x * 256 + threadIdx.x;      // 21504 total = 3*14*512
    const int kt = idx / 7168;
    const int r  = idx - kt * 7168;
    const int s2 = r >> 9;              // s*2 + mt
    const int l  = (r >> 3) & 63;
    const int j  = r & 7;
    const int co = (s2 & 1) * 16 + (l & 15);
    const int k  = (s2 >> 1) * 32 + (l >> 4) * 8 + j;
    u32 v = 0;
    if (k < 216) {
        const int ci = k & 7;
        const int combo = k >> 3;                         // (kd,kh,kw)
        const int kd = combo / 9;
        const int r9 = combo - kd * 9;
        const int kh = r9 / 3;
        const int kw = r9 - kh * 3;
        v = bf16r(wgt[((kt * 32 + co) * 8 + ci) * 27 + kd * 9 + kh * 3 + kw]);
    }
    wf[idx] = (u16)v;
}

// ---------- main kernel ----------
__global__ __launch_bounds__(320, 4) void conv4d_mfma(
    const u16* __restrict__ xtp, const u16* __restrict__ wf,
    const float* __restrict__ bias, float* __restrict__ out)
{
    __shared__ __align__(16) u16 sWf[7168];     // 14336 B: A-frags for current kt
    __shared__ __align__(16) u16 sHalo[10080];  // 20160 B: [d'3][h'10][w'42][ci8]
    __shared__ float sBsum[32];

    const int tid  = threadIdx.x;
    const int lane = tid & 63;
    const int wid  = tid >> 6;          // 0..4
    const int bi   = blockIdx.x;
    const int h0   = (bi % 5) * 8;
    const int d    = (bi / 5) % 40;
    const int o    = (bi / 200) % 16;
    const int b    = bi / 3200;

    if (tid < 32) {
        float s = 0.f;
        for (int kt = 0; kt < 3; ++kt) {
            int t = o + kt - 1;
            if ((unsigned)t < 16u) s += bias[kt * 32 + tid];
        }
        sBsum[tid] = s;
    }

    const int quad = lane >> 4;
    const int nl   = lane & 15;

    // per-lane n positions (4 n-tiles of 16)
    int hh[4], ww[4], lb[4];
#pragma unroll
    for (int tl = 0; tl < 4; ++tl) {
        int n = wid * 64 + tl * 16 + nl;   // 0..319
        hh[tl] = n / 40;
        ww[tl] = n - hh[tl] * 40;
        lb[tl] = (hh[tl] * 42 + ww[tl]) * 16;    // byte offset of cell (h'=hh, w'=ww) at d'=0
    }

    // per-lane combo offset per K-step (combo = 4s + quad), bytes
    int offs7[7];
#pragma unroll
    for (int s = 0; s < 7; ++s) {
        const int c0 = 4 * s;
        int O0 = (c0+0 < 27) ? (((c0+0)/9)*420 + (((c0+0)%9)/3)*42 + ((c0+0)%3)) * 16 : 0;
        int O1 = (c0+1 < 27) ? (((c0+1)/9)*420 + (((c0+1)%9)/3)*42 + ((c0+1)%3)) * 16 : 0;
        int O2 = (c0+2 < 27) ? (((c0+2)/9)*420 + (((c0+2)%9)/3)*42 + ((c0+2)%3)) * 16 : 0;
        int O3 = (c0+3 < 27) ? (((c0+3)/9)*420 + (((c0+3)%9)/3)*42 + ((c0+3)%3)) * 16 : 0;
        offs7[s] = (quad & 2) ? ((quad & 1) ? O3 : O2) : ((quad & 1) ? O1 : O0);
    }

    const f32x4 zero = {0.f, 0.f, 0.f, 0.f};
    f32x4 acc[2][4];
#pragma unroll
    for (int mt = 0; mt < 2; ++mt)
#pragma unroll
        for (int tl = 0; tl < 4; ++tl) acc[mt][tl] = zero;

#pragma unroll
    for (int kt = 0; kt < 3; ++kt) {
        const int t = o + kt - 1;
        if ((unsigned)t >= 16u) continue;            // block-uniform

        __syncthreads();   // previous iteration's LDS reads done

        // stage Wf slice for kt: 896 x 16B chunks, wave w -> [w*180, w*180+180) (clipped)
        {
            const u16* wfg = wf + kt * 7168;
            const int jb = wid * 180;
#pragma unroll
            for (int i = 0; i < 3; ++i) {
                const int io = i * 64 + lane;
                const int j = jb + io;
                if (io < 180 && j < 896) {
                    glds16(wfg + j * 8, (char*)sWf + (jb + i * 64) * 16);
                }
            }
        }
        // stage halo: 1260 x 16B chunks; rows (d',h') contiguous per d' (420 chunks each)
        {
            const u16* gbase = xtp + (size_t)(b * 16 + t) * 592704 + h0 * 336;
            const int jw = wid * 252;
#pragma unroll
            for (int i = 0; i < 4; ++i) {
                const int j = jw + i * 64 + lane;
                if (i < 3 || lane < 60) {
                    const int dpp = j / 420;       // 0..2
                    const int r = j - dpp * 420;
                    glds16(gbase + (d + dpp) * 14112 + r * 8, (char*)sHalo + (jw + i * 64) * 16);
                }
            }
        }
        __syncthreads();

        // K-loop: 7 steps of K=32 (4 combos/step), 8 MFMA per step per wave
#pragma unroll
        for (int s = 0; s < 7; ++s) {
            const short8 a0 = *(const short8*)((const char*)sWf + s * 2048 + lane * 16);
            const short8 a1 = *(const short8*)((const char*)sWf + s * 2048 + 1024 + lane * 16);
            const int off = offs7[s];
#pragma unroll
            for (int tl = 0; tl < 4; ++tl) {
                const short8 bf = *(const short8*)((const char*)sHalo + lb[tl] + off);
                acc[0][tl] = __builtin_amdgcn_mfma_f32_16x16x32_bf16(a0, bf, acc[0][tl], 0, 0, 0);
                acc[1][tl] = __builtin_amdgcn_mfma_f32_16x16x32_bf16(a1, bf, acc[1][tl], 0, 0, 0);
            }
        }
    }

    // epilogue: C/D layout col=lane&15 (n), row=quad*4+reg (co within 16-tile)
    const int coB = quad * 4;
    float bs[2][4];
#pragma unroll
    for (int mt = 0; mt < 2; ++mt)
#pragma unroll
        for (int reg = 0; reg < 4; ++reg) bs[mt][reg] = sBsum[mt * 16 + coB + reg];

#pragma unroll
    for (int mt = 0; mt < 2; ++mt)
#pragma unroll
        for (int tl = 0; tl < 4; ++tl) {
            const size_t base = (size_t)(((b * 32 + mt * 16 + coB) * 16 + o)) * 64000
                              + d * 1600 + (h0 + hh[tl]) * 40 + ww[tl];
#pragma unroll
            for (int reg = 0; reg < 4; ++reg)
                out[base + (size_t)reg * 1024000] = acc[mt][tl][reg] + bs[mt][reg];
        }
}

extern "C" void kernel_launch(void* const* d_in, const int* in_sizes, int n_in,
                              void* d_out, int out_size, void* d_ws, size_t ws_size,
                              hipStream_t stream)
{
    const float* x    = (const float*)d_in[0];
    const float* wgt  = (const float*)d_in[1];
    const float* bias = (const float*)d_in[2];
    float* out = (float*)d_out;
    u16* wfbuf = (u16*)d_ws;                                  // 43008 B
    u16* xtp   = (u16*)((char*)d_ws + XT_OFF_BYTES);          // 37,933,056 B
    (void)in_sizes; (void)n_in; (void)out_size; (void)ws_size;

    prep_w<<<dim3(84),   dim3(256), 0, stream>>>(wgt, wfbuf);
    prep_x<<<dim3(9261), dim3(256), 0, stream>>>(x, xtp);
    conv4d_mfma<<<dim3(6400), dim3(320), 0, stream>>>(xtp, wfbuf, bias, out);
}